// Round 2
// baseline (13124.139 us; speedup 1.0000x reference)
//
#include <hip/hip_runtime.h>
#include <math.h>

#define N_     64
#define Mn     2
#define Tn     300
#define Vn     25
#define Kk     3
#define CIN    3
#define CE     64
#define INTER_ 16
#define TV     7500
#define VV     625
#define ESEG   4      /* enc att t-segments (75 t each) */
#define DSEG   12     /* dec att t-segments (25 t each) */
#define TB     30     /* t-blocks for dy_stat / rr (10 t each) */
#define TT     10
#define EYB    12     /* ey_stat t-blocks (25 t each) */

/* ---------------- workspace layout (float offsets) ---------------- */
#define OFF_ATTP  0L         /* max N*K*DSEG*VV = 1,440,000 */
#define OFF_ATTE  1440000L   /* 2 * 120000 */
#define OFF_ATTD  1680000L   /* 2 * 120000 */
#define OFF_PART  1920000L   /* max N*TB*128 = 245,760 */
#define OFF_COV   2165760L   /* doubles: 120*9 -> 2160 floats */
#define OFF_PC    2167920L   /* 2 * 64*6 = 768 */
#define OFF_YC    2168688L   /* 2 * 64*2 = 256 */
#define OFF_TST   2168944L   /* 600 */
#define WS_REQ    2169600L

/* =================================================================
 * ENC ATT partials: fa[i,v]=sum_c x[c,t,v]*wa[k,i,c]+ba;
 * acc[v,w] += sum_i fa[i,v]*fb[i,w] over a t-segment.
 * ================================================================= */
__global__ __launch_bounds__(640)
void att_kernel(const float* __restrict__ xbase, long xn_stride, int xc_stride,
                const float* __restrict__ wa, const float* __restrict__ ba,
                const float* __restrict__ wb, const float* __restrict__ bb,
                float* __restrict__ att_partial)
{
    int b = blockIdx.x;
    int s = b % ESEG;
    int k = (b / ESEG) % Kk;
    int n = b / (ESEG * Kk);
    const float* xp = xbase + (long)n * xn_stride;

    __shared__ float xs[CIN][Vn];
    __shared__ float fa_s[INTER_][Vn];
    __shared__ float fb_s[INTER_][Vn];

    int tid = threadIdx.x;
    float acc = 0.f;
    const int TSEG = Tn / ESEG;
    int t0 = s * TSEG;
    for (int t = t0; t < t0 + TSEG; ++t) {
        __syncthreads();
        for (int idx = tid; idx < CIN * Vn; idx += 640) {
            int c = idx / Vn, v = idx % Vn;
            xs[c][v] = xp[(long)c * xc_stride + t * Vn + v];
        }
        __syncthreads();
        for (int idx = tid; idx < 2 * INTER_ * Vn; idx += 640) {
            int j = idx;
            const float* w; const float* bias; float (*dst)[Vn];
            if (j < INTER_ * Vn) { w = wa; bias = ba; dst = fa_s; }
            else { j -= INTER_ * Vn; w = wb; bias = bb; dst = fb_s; }
            int i = j / Vn, v = j % Vn;
            float sum = bias[k * INTER_ + i];
            const float* wr = w + (k * INTER_ + i) * CIN;
            #pragma unroll
            for (int c = 0; c < CIN; ++c) sum += wr[c] * xs[c][v];
            dst[i][v] = sum;
        }
        __syncthreads();
        if (tid < VV) {
            int v = tid / Vn, w = tid % Vn;
            float a = 0.f;
            #pragma unroll
            for (int i = 0; i < INTER_; ++i) a += fa_s[i][v] * fb_s[i][w];
            acc += a;
        }
    }
    if (tid < VV)
        att_partial[((long)(n * Kk + k) * ESEG + s) * VV + tid] = acc;
}

/* =================================================================
 * softmax over v (axis -2) per (n,k,w), then + (A + PA)
 * ================================================================= */
template<int SEGS>
__global__ __launch_bounds__(256)
void softmax_kernel(const float* __restrict__ att_partial,
                    const float* __restrict__ A, const float* __restrict__ PA,
                    float* __restrict__ att)
{
    int b = blockIdx.x;            /* n*K + k */
    int k = b % Kk;
    __shared__ float as[VV];
    int tid = threadIdx.x;
    for (int idx = tid; idx < VV; idx += 256) {
        float s = 0.f;
        for (int seg = 0; seg < SEGS; ++seg)
            s += att_partial[((long)b * SEGS + seg) * VV + idx];
        as[idx] = s * (1.0f / (INTER_ * Tn));
    }
    __syncthreads();
    if (tid < Vn) {
        int w = tid;
        float m = -1e30f;
        #pragma unroll
        for (int v = 0; v < Vn; ++v) m = fmaxf(m, as[v * Vn + w]);
        float e[Vn];
        float den = 0.f;
        #pragma unroll
        for (int v = 0; v < Vn; ++v) { e[v] = expf(as[v * Vn + w] - m); den += e[v]; }
        float inv = 1.f / den;
        #pragma unroll
        for (int v = 0; v < Vn; ++v)
            att[(long)b * VV + v * Vn + w] =
                e[v] * inv + A[k * VV + v * Vn + w] + PA[k * VV + v * Vn + w];
    }
}

/* =================================================================
 * x covariance (3 channels) partials for the enc down-BN stats
 * ================================================================= */
__global__ __launch_bounds__(256)
void xcov_kernel(const float* __restrict__ xbase, long xn_stride, int xc_stride,
                 double* __restrict__ part)
{
    double a[9];
    #pragma unroll
    for (int q = 0; q < 9; ++q) a[q] = 0.0;
    for (long idx = (long)blockIdx.x * 256 + threadIdx.x; idx < (long)N_ * TV;
         idx += (long)gridDim.x * 256) {
        int n = (int)(idx / TV);
        int j = (int)(idx % TV);
        const float* xp = xbase + (long)n * xn_stride + j;
        float x0 = xp[0], x1 = xp[xc_stride], x2 = xp[2 * xc_stride];
        a[0] += x0; a[1] += x1; a[2] += x2;
        a[3] += (double)x0 * x0; a[4] += (double)x0 * x1; a[5] += (double)x0 * x2;
        a[6] += (double)x1 * x1; a[7] += (double)x1 * x2; a[8] += (double)x2 * x2;
    }
    __shared__ double red[256];
    int tid = threadIdx.x;
    for (int q = 0; q < 9; ++q) {
        red[tid] = a[q];
        __syncthreads();
        for (int off = 128; off > 0; off >>= 1) {
            if (tid < off) red[tid] += red[tid + off];
            __syncthreads();
        }
        if (tid == 0) part[(long)blockIdx.x * 9 + q] = red[0];
        __syncthreads();
    }
}

/* =================================================================
 * ENC y stats (y computed WITHOUT bias; bias cancels in BN)
 * ================================================================= */
__global__ __launch_bounds__(256)
void ey_stat_kernel(const float* __restrict__ xb, const float* __restrict__ attE,
                    const float* __restrict__ ewd, float* __restrict__ part)
{
    __shared__ float attE_s[Kk][Vn][Vn];
    __shared__ float ewd_s[Kk * CE * CIN];
    __shared__ float xs[CIN][Vn];
    __shared__ float ez[Kk * CIN * Vn];
    __shared__ float ys[CE][Vn];
    int b = blockIdx.x, tb = b % EYB, n = b / EYB;
    int tid = threadIdx.x;
    for (int i = tid; i < Kk * VV; i += 256) ((float*)attE_s)[i] = attE[(long)n * Kk * VV + i];
    for (int i = tid; i < Kk * CE * CIN; i += 256) ewd_s[i] = ewd[i];
    float s1 = 0.f, s2 = 0.f;
    for (int t = tb * 25; t < tb * 25 + 25; ++t) {
        const float* xp = xb + (long)n * (Mn * CIN * TV) + t * Vn;
        __syncthreads();
        for (int i = tid; i < CIN * Vn; i += 256) { int c = i / Vn, v = i % Vn; xs[c][v] = xp[c * TV + v]; }
        __syncthreads();
        for (int i = tid; i < Kk * CIN * Vn; i += 256) {
            int w = i % Vn, c = (i / Vn) % CIN, k = i / (Vn * CIN);
            float s = 0.f;
            #pragma unroll
            for (int v = 0; v < Vn; ++v) s += xs[c][v] * attE_s[k][v][w];
            ez[i] = s;
        }
        __syncthreads();
        for (int i = tid; i < CE * Vn; i += 256) {
            int w = i % Vn, o = i / Vn;
            float y = 0.f;
            #pragma unroll
            for (int k = 0; k < Kk; ++k)
                #pragma unroll
                for (int c = 0; c < CIN; ++c)
                    y += ewd_s[(k * CE + o) * CIN + c] * ez[(k * CIN + c) * Vn + w];
            ys[o][w] = y;
        }
        __syncthreads();
        if (tid < CE) {
            #pragma unroll
            for (int w = 0; w < Vn; ++w) { float y = ys[tid][w]; s1 += y; s2 += y * y; }
        }
    }
    if (tid < CE) { part[(long)b * 128 + tid * 2] = s1; part[(long)b * 128 + tid * 2 + 1] = s2; }
}

/* =================================================================
 * ENC finalize: per-channel affine consts for p = relu(a*y + b + d.x + ...)
 * pc[o] = {alpha, constTotal, d0, d1, d2, 0}
 * ================================================================= */
__global__ __launch_bounds__(64)
void enc_fin_kernel(const float* __restrict__ part, int nparts,
                    const double* __restrict__ covp, int ncov,
                    const float* __restrict__ eg, const float* __restrict__ ebt,
                    const float* __restrict__ edw, const float* __restrict__ edb,
                    const float* __restrict__ edg, const float* __restrict__ edbt,
                    float* __restrict__ pc)
{
    int o = threadIdx.x;
    __shared__ double tot[9];
    if (o < 9) { double s = 0; for (int g = 0; g < ncov; ++g) s += covp[(long)g * 9 + o]; tot[o] = s; }
    double s1 = 0, s2 = 0;
    for (int b = 0; b < nparts; ++b) { s1 += part[(long)b * 128 + o * 2]; s2 += part[(long)b * 128 + o * 2 + 1]; }
    __syncthreads();
    double cnt = (double)N_ * Tn * Vn;
    double mean = s1 / cnt, var = s2 / cnt - mean * mean;
    double ersig = 1.0 / sqrt(var + 1e-5);
    double alpha = (double)eg[o] * ersig;
    double inv = 1.0 / cnt;
    double mu0 = tot[0] * inv, mu1 = tot[1] * inv, mu2 = tot[2] * inv;
    double c00 = tot[3] * inv - mu0 * mu0, c01 = tot[4] * inv - mu0 * mu1, c02 = tot[5] * inv - mu0 * mu2;
    double c11 = tot[6] * inv - mu1 * mu1, c12 = tot[7] * inv - mu1 * mu2, c22 = tot[8] * inv - mu2 * mu2;
    double w0 = edw[o * CIN + 0], w1 = edw[o * CIN + 1], w2 = edw[o * CIN + 2];
    double dmean = w0 * mu0 + w1 * mu1 + w2 * mu2 + (double)edb[o];
    double dvar = w0 * w0 * c00 + w1 * w1 * c11 + w2 * w2 * c22
                + 2.0 * (w0 * w1 * c01 + w0 * w2 * c02 + w1 * w2 * c12);
    double drsig = 1.0 / sqrt(dvar + 1e-5);
    double dga = (double)edg[o] * drsig;
    pc[o * 6 + 0] = (float)alpha;
    pc[o * 6 + 1] = (float)((double)ebt[o] - (double)eg[o] * mean * ersig
                            + dga * ((double)edb[o] - dmean) + (double)edbt[o]);
    pc[o * 6 + 2] = (float)(dga * w0);
    pc[o * 6 + 3] = (float)(dga * w1);
    pc[o * 6 + 4] = (float)(dga * w2);
    pc[o * 6 + 5] = 0.f;
}

/* =================================================================
 * Recompute the enc output tile p[64][25] at (n,t) in LDS.
 * ================================================================= */
__device__ __forceinline__ void penc_tile(int tid, int NT, const float* xp,
    const float (*attE_s)[Vn][Vn], const float* ewd_s, const float (*pc_s)[6],
    float (*xs)[Vn], float* ez, float (*ps)[Vn])
{
    __syncthreads();   /* protect xs/ez/ps from previous readers */
    for (int i = tid; i < CIN * Vn; i += NT) { int c = i / Vn, v = i % Vn; xs[c][v] = xp[c * TV + v]; }
    __syncthreads();
    for (int i = tid; i < Kk * CIN * Vn; i += NT) {
        int w = i % Vn, c = (i / Vn) % CIN, k = i / (Vn * CIN);
        float s = 0.f;
        #pragma unroll
        for (int v = 0; v < Vn; ++v) s += xs[c][v] * attE_s[k][v][w];
        ez[i] = s;
    }
    __syncthreads();
    for (int i = tid; i < CE * Vn; i += NT) {
        int w = i % Vn, o = i / Vn;
        float y = 0.f;
        #pragma unroll
        for (int k = 0; k < Kk; ++k)
            #pragma unroll
            for (int c = 0; c < CIN; ++c)
                y += ewd_s[(k * CE + o) * CIN + c] * ez[(k * CIN + c) * Vn + w];
        float val = pc_s[o][0] * y + pc_s[o][1]
                  + pc_s[o][2] * xs[0][w] + pc_s[o][3] * xs[1][w] + pc_s[o][4] * xs[2][w];
        ps[o][w] = fmaxf(val, 0.f);
    }
    __syncthreads();
}

/* =================================================================
 * DEC ATT: recompute p per t, fa/fb, accumulate att partials (all k)
 * ================================================================= */
__global__ __launch_bounds__(512)
void datt_kernel(const float* __restrict__ xb, const float* __restrict__ attE,
                 const float* __restrict__ ewd, const float* __restrict__ pc,
                 const float* __restrict__ dwa, const float* __restrict__ dba,
                 const float* __restrict__ dwb, const float* __restrict__ dbb,
                 float* __restrict__ attp)
{
    __shared__ float attE_s[Kk][Vn][Vn];
    __shared__ float ewd_s[Kk * CE * CIN];
    __shared__ float pc_s[CE][6];
    __shared__ float wa_s[Kk * INTER_ * CE];
    __shared__ float wb_s[Kk * INTER_ * CE];
    __shared__ float ba_s[Kk * INTER_], bb_s[Kk * INTER_];
    __shared__ float xs[CIN][Vn];
    __shared__ float ez[Kk * CIN * Vn];
    __shared__ float ps[CE][Vn];
    __shared__ float fa[Kk][INTER_][Vn], fb[Kk][INTER_][Vn];
    int b = blockIdx.x, s = b % DSEG, n = b / DSEG;
    int tid = threadIdx.x;
    for (int i = tid; i < Kk * VV; i += 512) ((float*)attE_s)[i] = attE[(long)n * Kk * VV + i];
    for (int i = tid; i < Kk * CE * CIN; i += 512) ewd_s[i] = ewd[i];
    for (int i = tid; i < CE * 6; i += 512) ((float*)pc_s)[i] = pc[i];
    for (int i = tid; i < Kk * INTER_ * CE; i += 512) { wa_s[i] = dwa[i]; wb_s[i] = dwb[i]; }
    for (int i = tid; i < Kk * INTER_; i += 512) { ba_s[i] = dba[i]; bb_s[i] = dbb[i]; }
    float acc[4] = {0.f, 0.f, 0.f, 0.f};
    const int TS = Tn / DSEG;   /* 25 */
    for (int t = s * TS; t < s * TS + TS; ++t) {
        const float* xp = xb + (long)n * (Mn * CIN * TV) + t * Vn;
        penc_tile(tid, 512, xp, attE_s, ewd_s, pc_s, xs, ez, ps);
        for (int i = tid; i < 2 * Kk * INTER_ * Vn; i += 512) {
            int j = i;
            int sel = j >= Kk * INTER_ * Vn;
            if (sel) j -= Kk * INTER_ * Vn;
            int v = j % Vn, ki = j / Vn;
            const float* W = sel ? wb_s : wa_s;
            float sum = (sel ? bb_s : ba_s)[ki];
            const float* wr = W + ki * CE;
            #pragma unroll
            for (int c = 0; c < CE; ++c) sum += wr[c] * ps[c][v];
            float* dst = sel ? (float*)fb : (float*)fa;
            dst[j] = sum;
        }
        __syncthreads();
        #pragma unroll
        for (int m = 0; m < 4; ++m) {
            int idx = tid + 512 * m;
            if (idx < Kk * VV) {
                int k = idx / VV, r = idx % VV, v = r / Vn, w = r % Vn;
                float a = 0.f;
                #pragma unroll
                for (int i = 0; i < INTER_; ++i) a += fa[k][i][v] * fb[k][i][w];
                acc[m] += a;
            }
        }
    }
    #pragma unroll
    for (int m = 0; m < 4; ++m) {
        int idx = tid + 512 * m;
        if (idx < Kk * VV) {
            int k = idx / VV, r = idx % VV;
            attp[(((long)n * Kk + k) * DSEG + s) * VV + r] = acc[m];
        }
    }
}

/* =================================================================
 * DEC y stats: recompute p, dz (per k), dy (raw, no bias), accumulate
 * ================================================================= */
__global__ __launch_bounds__(512)
void dy_stat_kernel(const float* __restrict__ xb, const float* __restrict__ attE,
                    const float* __restrict__ attD, const float* __restrict__ ewd,
                    const float* __restrict__ pc, const float* __restrict__ dwd,
                    float* __restrict__ part)
{
    __shared__ float attE_s[Kk][Vn][Vn];
    __shared__ float attD_s[Kk][Vn][Vn];
    __shared__ float ewd_s[Kk * CE * CIN];
    __shared__ float pc_s[CE][6];
    __shared__ float dwd_s[CE][65];
    __shared__ float xs[CIN][Vn];
    __shared__ float ezdz[CE * 32];    /* union: ez (225) / dz padded [64][32] */
    __shared__ float ps[CE][Vn];
    __shared__ float red[512];
    int b = blockIdx.x, tb = b % TB, n = b / TB;
    int tid = threadIdx.x;
    for (int i = tid; i < Kk * VV; i += 512) {
        ((float*)attE_s)[i] = attE[(long)n * Kk * VV + i];
        ((float*)attD_s)[i] = attD[(long)n * Kk * VV + i];
    }
    for (int i = tid; i < Kk * CE * CIN; i += 512) ewd_s[i] = ewd[i];
    for (int i = tid; i < CE * 6; i += 512) ((float*)pc_s)[i] = pc[i];
    int o = tid >> 3, q = tid & 7;
    float s1 = 0.f, s2 = 0.f;
    for (int t = tb * TT; t < tb * TT + TT; ++t) {
        const float* xp = xb + (long)n * (Mn * CIN * TV) + t * Vn;
        penc_tile(tid, 512, xp, attE_s, ewd_s, pc_s, xs, ezdz, ps);
        float acc[4] = {0.f, 0.f, 0.f, 0.f};
        for (int k = 0; k < Kk; ++k) {
            if (k) __syncthreads();
            for (int i = tid; i < CE * CE; i += 512) {
                int oo = i >> 6, cc = i & 63;
                dwd_s[oo][cc] = dwd[((long)k * CE + oo) * CE + cc];
            }
            for (int i = tid; i < CE * 32; i += 512) {
                int c = i >> 5, w = i & 31;
                float sum = 0.f;
                if (w < Vn) {
                    #pragma unroll
                    for (int v = 0; v < Vn; ++v) sum += ps[c][v] * attD_s[k][v][w];
                }
                ezdz[i] = sum;
            }
            __syncthreads();
            #pragma unroll
            for (int c = 0; c < CE; ++c) {
                float wv = dwd_s[o][c];
                const float* dzr = &ezdz[c * 32];
                #pragma unroll
                for (int m = 0; m < 4; ++m) acc[m] += wv * dzr[q + 8 * m];
            }
        }
        #pragma unroll
        for (int m = 0; m < 4; ++m) {
            int w = q + 8 * m;
            if (w < Vn) { s1 += acc[m]; s2 += acc[m] * acc[m]; }
        }
    }
    red[tid] = s1;
    __syncthreads();
    float t1 = 0.f;
    if (q == 0) { for (int j = 0; j < 8; ++j) t1 += red[(o << 3) + j]; }
    __syncthreads();
    red[tid] = s2;
    __syncthreads();
    if (q == 0) {
        float t2 = 0.f;
        for (int j = 0; j < 8; ++j) t2 += red[(o << 3) + j];
        part[(long)b * 128 + o * 2 + 0] = t1;
        part[(long)b * 128 + o * 2 + 1] = t2;
    }
}

__global__ __launch_bounds__(64)
void dec_fin_kernel(const float* __restrict__ part, int nparts,
                    const float* __restrict__ dg, const float* __restrict__ dbt,
                    float* __restrict__ yc)
{
    int o = threadIdx.x;
    double s1 = 0, s2 = 0;
    for (int b = 0; b < nparts; ++b) { s1 += part[(long)b * 128 + o * 2]; s2 += part[(long)b * 128 + o * 2 + 1]; }
    double cnt = (double)N_ * Tn * Vn;
    double mean = s1 / cnt, var = s2 / cnt - mean * mean;
    double rsig = 1.0 / sqrt(var + 1e-5);
    double a = (double)dg[o] * rsig;
    yc[o * 2 + 0] = (float)a;
    yc[o * 2 + 1] = (float)((double)dbt[o] - a * mean);
}

/* =================================================================
 * RR: recompute both branches' dec outputs per (n,t), write RAM_r
 * to d_out.
 * ================================================================= */
__global__ __launch_bounds__(512)
void rr2_kernel(const float* __restrict__ x, const float* __restrict__ attEb,
                const float* __restrict__ attDb, const float* __restrict__ ewd,
                const float* __restrict__ pcb, const float* __restrict__ ycb,
                const float* __restrict__ dwd, float* __restrict__ out)
{
    __shared__ float attX_s[Kk][Vn][Vn];
    __shared__ float attDk[VV];
    __shared__ float ewd_s[Kk * CE * CIN];
    __shared__ float pc_s[2][CE][6];
    __shared__ float yc_s[2][CE][2];
    __shared__ float dwd_s[CE][65];
    __shared__ float xs[CIN][Vn];
    __shared__ float ezdz[CE * 32];
    __shared__ float ps0[CE][Vn], ps1[CE][Vn];
    int b = blockIdx.x, tb = b % TB, n = b / TB;
    int tid = threadIdx.x;
    for (int i = tid; i < Kk * CE * CIN; i += 512) ewd_s[i] = ewd[i];
    for (int i = tid; i < 2 * CE * 6; i += 512) ((float*)pc_s)[i] = pcb[i];
    for (int i = tid; i < 2 * CE * 2; i += 512) ((float*)yc_s)[i] = ycb[i];
    int o = tid >> 3, q = tid & 7;
    for (int t = tb * TT; t < tb * TT + TT; ++t) {
        float acc0[4] = {0.f, 0.f, 0.f, 0.f};
        float acc1[4] = {0.f, 0.f, 0.f, 0.f};
        /* --- recompute enc outputs for both branches --- */
        __syncthreads();
        for (int i = tid; i < Kk * VV; i += 512)
            ((float*)attX_s)[i] = attEb[((long)0 * N_ + n) * Kk * VV + i];
        penc_tile(tid, 512, x + (long)n * (Mn * CIN * TV) + 0 * (CIN * TV) + t * Vn,
                  attX_s, ewd_s, pc_s[0], xs, ezdz, ps0);
        __syncthreads();
        for (int i = tid; i < Kk * VV; i += 512)
            ((float*)attX_s)[i] = attEb[((long)1 * N_ + n) * Kk * VV + i];
        penc_tile(tid, 512, x + (long)n * (Mn * CIN * TV) + 1 * (CIN * TV) + t * Vn,
                  attX_s, ewd_s, pc_s[1], xs, ezdz, ps1);
        /* --- dec y for both branches, k at a time --- */
        for (int k = 0; k < Kk; ++k) {
            __syncthreads();
            for (int i = tid; i < CE * CE; i += 512) {
                int oo = i >> 6, cc = i & 63;
                dwd_s[oo][cc] = dwd[((long)k * CE + oo) * CE + cc];
            }
            /* branch 0 */
            for (int i = tid; i < VV; i += 512)
                attDk[i] = attDb[(((long)0 * N_ + n) * Kk + k) * VV + i];
            __syncthreads();
            for (int i = tid; i < CE * 32; i += 512) {
                int c = i >> 5, w = i & 31;
                float sum = 0.f;
                if (w < Vn) {
                    #pragma unroll
                    for (int v = 0; v < Vn; ++v) sum += ps0[c][v] * attDk[v * Vn + w];
                }
                ezdz[i] = sum;
            }
            __syncthreads();
            #pragma unroll
            for (int c = 0; c < CE; ++c) {
                float wv = dwd_s[o][c];
                const float* dzr = &ezdz[c * 32];
                #pragma unroll
                for (int m = 0; m < 4; ++m) acc0[m] += wv * dzr[q + 8 * m];
            }
            __syncthreads();
            /* branch 1 */
            for (int i = tid; i < VV; i += 512)
                attDk[i] = attDb[(((long)1 * N_ + n) * Kk + k) * VV + i];
            __syncthreads();
            for (int i = tid; i < CE * 32; i += 512) {
                int c = i >> 5, w = i & 31;
                float sum = 0.f;
                if (w < Vn) {
                    #pragma unroll
                    for (int v = 0; v < Vn; ++v) sum += ps1[c][v] * attDk[v * Vn + w];
                }
                ezdz[i] = sum;
            }
            __syncthreads();
            #pragma unroll
            for (int c = 0; c < CE; ++c) {
                float wv = dwd_s[o][c];
                const float* dzr = &ezdz[c * 32];
                #pragma unroll
                for (int m = 0; m < 4; ++m) acc1[m] += wv * dzr[q + 8 * m];
            }
        }
        __syncthreads();
        /* apply dec bn + residual + relu; write over ps0/ps1 */
        #pragma unroll
        for (int m = 0; m < 4; ++m) {
            int w = q + 8 * m;
            if (w < Vn) {
                float v0 = yc_s[0][o][0] * acc0[m] + yc_s[0][o][1] + ps0[o][w];
                ps0[o][w] = fmaxf(v0, 0.f);
                float v1 = yc_s[1][o][0] * acc1[m] + yc_s[1][o][1] + ps1[o][w];
                ps1[o][w] = fmaxf(v1, 0.f);
            }
        }
        __syncthreads();
        for (int i = tid; i < VV; i += 512) {
            int v = i / Vn, w = i % Vn;
            float s = 0.f;
            #pragma unroll
            for (int c = 0; c < CE; ++c) s += ps0[c][v] * ps1[c][w];
            out[((long)n * Tn + t) * VV + i] = s;
        }
    }
}

/* BN stats over (n,v,w) per t */
__global__ __launch_bounds__(256)
void rrbn_kernel(const float* __restrict__ rr, float* __restrict__ tstats)
{
    int t = blockIdx.x;
    double s = 0.0, s2 = 0.0;
    for (int idx = threadIdx.x; idx < N_ * VV; idx += 256) {
        int n = idx / VV, j = idx % VV;
        float v = rr[((long)n * Tn + t) * VV + j];
        s += v; s2 += (double)v * v;
    }
    __shared__ double rs[256], rs2[256];
    int tid = threadIdx.x;
    rs[tid] = s; rs2[tid] = s2;
    __syncthreads();
    for (int off = 128; off > 0; off >>= 1) {
        if (tid < off) { rs[tid] += rs[tid + off]; rs2[tid] += rs2[tid + off]; }
        __syncthreads();
    }
    if (tid == 0) {
        double cnt = (double)N_ * VV;
        double mean = rs[0] / cnt;
        double var = rs2[0] / cnt - mean * mean;
        tstats[t * 2 + 0] = (float)mean;
        tstats[t * 2 + 1] = (float)(1.0 / sqrt(var + 1e-5));
    }
}

/* =================================================================
 * FINAL: RAM_g, BN(RAM_r)+tanh, integration, ab mask, threshold,
 * row/col norm — in place on d_out.
 * ================================================================= */
__global__ __launch_bounds__(128)
void final_kernel(const float* __restrict__ tstats,
                  const float* __restrict__ x, const float* __restrict__ iparam,
                  const float* __restrict__ tgamma, const float* __restrict__ tbeta,
                  float* out)
{
    int b = blockIdx.x;            /* n*T + t */
    int t = b % Tn, n = b / Tn;
    __shared__ float xa_s[CIN][Vn], xb_s[CIN][Vn];
    __shared__ float ram_s[VV];
    __shared__ float da_s[Vn], db_s[Vn];
    __shared__ float varc[CIN];
    __shared__ float abf;
    int tid = threadIdx.x;

    for (int idx = tid; idx < 2 * CIN * Vn; idx += 128) {
        int half = idx / (CIN * Vn);
        int r = idx % (CIN * Vn);
        int c = r / Vn, v = r % Vn;
        float val = x[(((long)n * Mn + half) * CIN + c) * TV + t * Vn + v];
        if (half == 0) xa_s[c][v] = val; else xb_s[c][v] = val;
    }
    __syncthreads();
    if (tid < CIN) {
        float s = 0.f, s2 = 0.f;
        #pragma unroll
        for (int v = 0; v < Vn; ++v) { float q = xb_s[tid][v]; s += q; s2 += q * q; }
        float mean = s / Vn;
        varc[tid] = (s2 - Vn * mean * mean) / (Vn - 1);
    }
    __syncthreads();
    if (tid == 0) {
        float absum = varc[0] + varc[1] + varc[2];
        abf = (absum < 1e-4f) ? 0.f : 1.f;
    }
    float pct = 0.5f * (tanhf(iparam[0]) + 1.f);
    float mt = tstats[t * 2], rt = tstats[t * 2 + 1];
    float gt = tgamma[t], bt = tbeta[t];
    __syncthreads();

    for (int idx = tid; idx < VV; idx += 128) {
        int v = idx / Vn, w = idx % Vn;
        float rrv = out[(long)b * VV + idx];
        float rbn = gt * (rrv - mt) * rt + bt;
        float ramr = 0.5f * (tanhf(rbn) + 1.f);
        float gsum = 0.f;
        #pragma unroll
        for (int c = 0; c < CIN; ++c) {
            float d = expf(xa_s[c][v]) * expf(-xb_s[c][w]);
            float l = logf(d + 1e-5f);
            gsum += l * l;
        }
        float ramg = expf(-(1.f / 3.f) * gsum);
        float ram = pct * ramr + (1.f - pct) * ramg;
        ram *= abf;
        if (ram < 0.5f) ram = 0.f;
        ram_s[idx] = ram;
    }
    __syncthreads();
    if (tid < Vn) {
        float s = 0.f;
        #pragma unroll
        for (int v = 0; v < Vn; ++v) s += ram_s[v * Vn + tid];
        da_s[tid] = s;
    } else if (tid >= 64 && tid < 64 + Vn) {
        int v = tid - 64;
        float s = 0.f;
        #pragma unroll
        for (int w = 0; w < Vn; ++w) s += ram_s[v * Vn + w];
        db_s[v] = s;
    }
    __syncthreads();
    for (int idx = tid; idx < VV; idx += 128) {
        int v = idx / Vn, w = idx % Vn;
        float ram = ram_s[idx];
        out[(long)b * VV + idx] = ram * rsqrtf(db_s[v] * da_s[w] + 1e-5f);
    }
}

/* ================================================================= */
extern "C" void kernel_launch(void* const* d_in, const int* in_sizes, int n_in,
                              void* d_out, int out_size, void* d_ws, size_t ws_size,
                              hipStream_t stream)
{
    const float* x    = (const float*)d_in[0];
    const float* A    = (const float*)d_in[1];
    const float* ip   = (const float*)d_in[2];
    const float* rg   = (const float*)d_in[3];
    const float* rbta = (const float*)d_in[4];
    const float* ePA  = (const float*)d_in[5];
    const float* ewa  = (const float*)d_in[6];
    const float* eba  = (const float*)d_in[7];
    const float* ewb  = (const float*)d_in[8];
    const float* ebb  = (const float*)d_in[9];
    const float* ewd  = (const float*)d_in[10];
    const float* ebd  = (const float*)d_in[11];  (void)ebd;   /* cancels in BN */
    const float* eg   = (const float*)d_in[12];
    const float* ebt  = (const float*)d_in[13];
    const float* edw  = (const float*)d_in[14];
    const float* edb  = (const float*)d_in[15];
    const float* edg  = (const float*)d_in[16];
    const float* edbt = (const float*)d_in[17];
    const float* dPA  = (const float*)d_in[18];
    const float* dwa  = (const float*)d_in[19];
    const float* dba  = (const float*)d_in[20];
    const float* dwb  = (const float*)d_in[21];
    const float* dbb  = (const float*)d_in[22];
    const float* dwd  = (const float*)d_in[23];
    const float* dbd  = (const float*)d_in[24];  (void)dbd;   /* cancels in BN */
    const float* dg   = (const float*)d_in[25];
    const float* dbt  = (const float*)d_in[26];

    if (ws_size < (size_t)WS_REQ * sizeof(float)) return;

    float* ws   = (float*)d_ws;
    float* attp = ws + OFF_ATTP;
    float* attE = ws + OFF_ATTE;
    float* attD = ws + OFF_ATTD;
    float* part = ws + OFF_PART;
    double* covp = (double*)(ws + OFF_COV);
    float* pc   = ws + OFF_PC;
    float* yc   = ws + OFF_YC;
    float* tst  = ws + OFF_TST;
    float* outf = (float*)d_out;

    const long XN = (long)Mn * CIN * TV;   /* 45000 */

    for (int br = 0; br < 2; ++br) {
        const float* xbr = x + (long)br * CIN * TV;
        float* attE_br = attE + (long)br * (N_ * Kk * VV);
        float* attD_br = attD + (long)br * (N_ * Kk * VV);
        float* pc_br = pc + br * (CE * 6);
        float* yc_br = yc + br * (CE * 2);

        att_kernel<<<N_ * Kk * ESEG, 640, 0, stream>>>(
            xbr, XN, TV, ewa, eba, ewb, ebb, attp);
        softmax_kernel<ESEG><<<N_ * Kk, 256, 0, stream>>>(attp, A, ePA, attE_br);
        xcov_kernel<<<120, 256, 0, stream>>>(xbr, XN, TV, covp);
        ey_stat_kernel<<<N_ * EYB, 256, 0, stream>>>(xbr, attE_br, ewd, part);
        enc_fin_kernel<<<1, 64, 0, stream>>>(part, N_ * EYB, covp, 120,
                                             eg, ebt, edw, edb, edg, edbt, pc_br);
        datt_kernel<<<N_ * DSEG, 512, 0, stream>>>(
            xbr, attE_br, ewd, pc_br, dwa, dba, dwb, dbb, attp);
        softmax_kernel<DSEG><<<N_ * Kk, 256, 0, stream>>>(attp, A, dPA, attD_br);
        dy_stat_kernel<<<N_ * TB, 512, 0, stream>>>(
            xbr, attE_br, attD_br, ewd, pc_br, dwd, part);
        dec_fin_kernel<<<1, 64, 0, stream>>>(part, N_ * TB, dg, dbt, yc_br);
    }

    rr2_kernel<<<N_ * TB, 512, 0, stream>>>(x, attE, attD, ewd, pc, yc, dwd, outf);
    rrbn_kernel<<<Tn, 256, 0, stream>>>(outf, tst);
    final_kernel<<<N_ * Tn, 128, 0, stream>>>(tst, x, ip, rg, rbta, outf);
}

// Round 5
// 5712.907 us; speedup vs baseline: 2.2973x; 2.2973x over previous
//
#include <hip/hip_runtime.h>
#include <math.h>

#define N_     64
#define Mn     2
#define Tn     300
#define Vn     25
#define Kk     3
#define CIN    3
#define CE     64
#define INTER_ 16
#define TV     7500
#define VV     625
#define ESEG   4      /* enc att t-segments (75 t each) */
#define DSEG   12     /* dec att t-segments (25 t each) */
#define TB     30     /* t-blocks for decy (10 t each) */
#define TT     10
#define EYB    12     /* ey_stat t-blocks (25 t each) */

typedef float f4 __attribute__((ext_vector_type(4)));
typedef float f2 __attribute__((ext_vector_type(2)));

/* ---------------- workspace layout (float offsets) ----------------
 * attp/part share region 0 (disjoint lifetimes). */
#define OFF_ATTP  0L         /* max(N*K*DSEG*VV, 2*N*TB*128) = 1,440,000 */
#define OFF_PART  0L
#define OFF_ATTE  1440000L   /* 2 * 120000 */
#define OFF_ATTD  1680000L   /* 2 * 120000 */
#define OFF_COV   1920000L   /* doubles: 120*9 -> 2160 floats */
#define OFF_PC    1922160L   /* 2 * 64*6 = 768 */
#define OFF_YC    1922928L   /* 2 * 64*2 = 256 */
#define OFF_TST   1923184L   /* 600 */
#define WS_REQ    1923784L

/* =================================================================
 * ENC ATT partials
 * ================================================================= */
__global__ __launch_bounds__(640)
void att_kernel(const float* __restrict__ xbase, long xn_stride, int xc_stride,
                const float* __restrict__ wa, const float* __restrict__ ba,
                const float* __restrict__ wb, const float* __restrict__ bb,
                float* __restrict__ att_partial)
{
    int b = blockIdx.x;
    int s = b % ESEG;
    int k = (b / ESEG) % Kk;
    int n = b / (ESEG * Kk);
    const float* xp = xbase + (long)n * xn_stride;

    __shared__ float xs[CIN][Vn];
    __shared__ float fa_s[INTER_][Vn];
    __shared__ float fb_s[INTER_][Vn];

    int tid = threadIdx.x;
    float acc = 0.f;
    const int TSEG = Tn / ESEG;
    int t0 = s * TSEG;
    for (int t = t0; t < t0 + TSEG; ++t) {
        __syncthreads();
        for (int idx = tid; idx < CIN * Vn; idx += 640) {
            int c = idx / Vn, v = idx % Vn;
            xs[c][v] = xp[(long)c * xc_stride + t * Vn + v];
        }
        __syncthreads();
        for (int idx = tid; idx < 2 * INTER_ * Vn; idx += 640) {
            int j = idx;
            const float* w; const float* bias; float (*dst)[Vn];
            if (j < INTER_ * Vn) { w = wa; bias = ba; dst = fa_s; }
            else { j -= INTER_ * Vn; w = wb; bias = bb; dst = fb_s; }
            int i = j / Vn, v = j % Vn;
            float sum = bias[k * INTER_ + i];
            const float* wr = w + (k * INTER_ + i) * CIN;
            #pragma unroll
            for (int c = 0; c < CIN; ++c) sum += wr[c] * xs[c][v];
            dst[i][v] = sum;
        }
        __syncthreads();
        if (tid < VV) {
            int v = tid / Vn, w = tid % Vn;
            float a = 0.f;
            #pragma unroll
            for (int i = 0; i < INTER_; ++i) a += fa_s[i][v] * fb_s[i][w];
            acc += a;
        }
    }
    if (tid < VV)
        att_partial[((long)(n * Kk + k) * ESEG + s) * VV + tid] = acc;
}

/* softmax over v per (n,k,w), then + (A+PA) */
template<int SEGS>
__global__ __launch_bounds__(256)
void softmax_kernel(const float* __restrict__ att_partial,
                    const float* __restrict__ A, const float* __restrict__ PA,
                    float* __restrict__ att)
{
    int b = blockIdx.x;            /* n*K + k */
    int k = b % Kk;
    __shared__ float as[VV];
    int tid = threadIdx.x;
    for (int idx = tid; idx < VV; idx += 256) {
        float s = 0.f;
        for (int seg = 0; seg < SEGS; ++seg)
            s += att_partial[((long)b * SEGS + seg) * VV + idx];
        as[idx] = s * (1.0f / (INTER_ * Tn));
    }
    __syncthreads();
    if (tid < Vn) {
        int w = tid;
        float m = -1e30f;
        #pragma unroll
        for (int v = 0; v < Vn; ++v) m = fmaxf(m, as[v * Vn + w]);
        float e[Vn];
        float den = 0.f;
        #pragma unroll
        for (int v = 0; v < Vn; ++v) { e[v] = expf(as[v * Vn + w] - m); den += e[v]; }
        float inv = 1.f / den;
        #pragma unroll
        for (int v = 0; v < Vn; ++v)
            att[(long)b * VV + v * Vn + w] =
                e[v] * inv + A[k * VV + v * Vn + w] + PA[k * VV + v * Vn + w];
    }
}

/* x covariance partials */
__global__ __launch_bounds__(256)
void xcov_kernel(const float* __restrict__ xbase, long xn_stride, int xc_stride,
                 double* __restrict__ part)
{
    double a[9];
    #pragma unroll
    for (int q = 0; q < 9; ++q) a[q] = 0.0;
    for (long idx = (long)blockIdx.x * 256 + threadIdx.x; idx < (long)N_ * TV;
         idx += (long)gridDim.x * 256) {
        int n = (int)(idx / TV);
        int j = (int)(idx % TV);
        const float* xp = xbase + (long)n * xn_stride + j;
        float x0 = xp[0], x1 = xp[xc_stride], x2 = xp[2 * xc_stride];
        a[0] += x0; a[1] += x1; a[2] += x2;
        a[3] += (double)x0 * x0; a[4] += (double)x0 * x1; a[5] += (double)x0 * x2;
        a[6] += (double)x1 * x1; a[7] += (double)x1 * x2; a[8] += (double)x2 * x2;
    }
    __shared__ double red[256];
    int tid = threadIdx.x;
    for (int q = 0; q < 9; ++q) {
        red[tid] = a[q];
        __syncthreads();
        for (int off = 128; off > 0; off >>= 1) {
            if (tid < off) red[tid] += red[tid + off];
            __syncthreads();
        }
        if (tid == 0) part[(long)blockIdx.x * 9 + q] = red[0];
        __syncthreads();
    }
}

/* ENC y stats */
__global__ __launch_bounds__(256)
void ey_stat_kernel(const float* __restrict__ xb, const float* __restrict__ attE,
                    const float* __restrict__ ewd, float* __restrict__ part)
{
    __shared__ float attE_s[Kk][Vn][Vn];
    __shared__ float ewd_s[Kk * CE * CIN];
    __shared__ float xs[CIN][Vn];
    __shared__ float ez[Kk * CIN * Vn];
    __shared__ float ys[CE][Vn];
    int b = blockIdx.x, tb = b % EYB, n = b / EYB;
    int tid = threadIdx.x;
    for (int i = tid; i < Kk * VV; i += 256) ((float*)attE_s)[i] = attE[(long)n * Kk * VV + i];
    for (int i = tid; i < Kk * CE * CIN; i += 256) ewd_s[i] = ewd[i];
    float s1 = 0.f, s2 = 0.f;
    for (int t = tb * 25; t < tb * 25 + 25; ++t) {
        const float* xp = xb + (long)n * (Mn * CIN * TV) + t * Vn;
        __syncthreads();
        for (int i = tid; i < CIN * Vn; i += 256) { int c = i / Vn, v = i % Vn; xs[c][v] = xp[c * TV + v]; }
        __syncthreads();
        for (int i = tid; i < Kk * CIN * Vn; i += 256) {
            int w = i % Vn, c = (i / Vn) % CIN, k = i / (Vn * CIN);
            float s = 0.f;
            #pragma unroll
            for (int v = 0; v < Vn; ++v) s += xs[c][v] * attE_s[k][v][w];
            ez[i] = s;
        }
        __syncthreads();
        for (int i = tid; i < CE * Vn; i += 256) {
            int w = i % Vn, o = i / Vn;
            float y = 0.f;
            #pragma unroll
            for (int k = 0; k < Kk; ++k)
                #pragma unroll
                for (int c = 0; c < CIN; ++c)
                    y += ewd_s[(k * CE + o) * CIN + c] * ez[(k * CIN + c) * Vn + w];
            ys[o][w] = y;
        }
        __syncthreads();
        if (tid < CE) {
            #pragma unroll
            for (int w = 0; w < Vn; ++w) { float y = ys[tid][w]; s1 += y; s2 += y * y; }
        }
    }
    if (tid < CE) { part[(long)b * 128 + tid * 2] = s1; part[(long)b * 128 + tid * 2 + 1] = s2; }
}

/* ENC finalize */
__global__ __launch_bounds__(64)
void enc_fin_kernel(const float* __restrict__ part, int nparts,
                    const double* __restrict__ covp, int ncov,
                    const float* __restrict__ eg, const float* __restrict__ ebt,
                    const float* __restrict__ edw, const float* __restrict__ edb,
                    const float* __restrict__ edg, const float* __restrict__ edbt,
                    float* __restrict__ pc)
{
    int o = threadIdx.x;
    __shared__ double tot[9];
    if (o < 9) { double s = 0; for (int g = 0; g < ncov; ++g) s += covp[(long)g * 9 + o]; tot[o] = s; }
    double s1 = 0, s2 = 0;
    for (int b = 0; b < nparts; ++b) { s1 += part[(long)b * 128 + o * 2]; s2 += part[(long)b * 128 + o * 2 + 1]; }
    __syncthreads();
    double cnt = (double)N_ * Tn * Vn;
    double mean = s1 / cnt, var = s2 / cnt - mean * mean;
    double ersig = 1.0 / sqrt(var + 1e-5);
    double alpha = (double)eg[o] * ersig;
    double inv = 1.0 / cnt;
    double mu0 = tot[0] * inv, mu1 = tot[1] * inv, mu2 = tot[2] * inv;
    double c00 = tot[3] * inv - mu0 * mu0, c01 = tot[4] * inv - mu0 * mu1, c02 = tot[5] * inv - mu0 * mu2;
    double c11 = tot[6] * inv - mu1 * mu1, c12 = tot[7] * inv - mu1 * mu2, c22 = tot[8] * inv - mu2 * mu2;
    double w0 = edw[o * CIN + 0], w1 = edw[o * CIN + 1], w2 = edw[o * CIN + 2];
    double dmean = w0 * mu0 + w1 * mu1 + w2 * mu2 + (double)edb[o];
    double dvar = w0 * w0 * c00 + w1 * w1 * c11 + w2 * w2 * c22
                + 2.0 * (w0 * w1 * c01 + w0 * w2 * c02 + w1 * w2 * c12);
    double drsig = 1.0 / sqrt(dvar + 1e-5);
    double dga = (double)edg[o] * drsig;
    pc[o * 6 + 0] = (float)alpha;
    pc[o * 6 + 1] = (float)((double)ebt[o] - (double)eg[o] * mean * ersig
                            + dga * ((double)edb[o] - dmean) + (double)edbt[o]);
    pc[o * 6 + 2] = (float)(dga * w0);
    pc[o * 6 + 3] = (float)(dga * w1);
    pc[o * 6 + 4] = (float)(dga * w2);
    pc[o * 6 + 5] = 0.f;
}

/* penc helper for datt */
__device__ __forceinline__ void penc_tile(int tid, int NT, const float* xp,
    const float (*attE_s)[Vn][Vn], const float* ewd_s, const float (*pc_s)[6],
    float (*xs)[Vn], float* ez, float (*ps)[Vn])
{
    __syncthreads();
    for (int i = tid; i < CIN * Vn; i += NT) { int c = i / Vn, v = i % Vn; xs[c][v] = xp[c * TV + v]; }
    __syncthreads();
    for (int i = tid; i < Kk * CIN * Vn; i += NT) {
        int w = i % Vn, c = (i / Vn) % CIN, k = i / (Vn * CIN);
        float s = 0.f;
        #pragma unroll
        for (int v = 0; v < Vn; ++v) s += xs[c][v] * attE_s[k][v][w];
        ez[i] = s;
    }
    __syncthreads();
    for (int i = tid; i < CE * Vn; i += NT) {
        int w = i % Vn, o = i / Vn;
        float y = 0.f;
        #pragma unroll
        for (int k = 0; k < Kk; ++k)
            #pragma unroll
            for (int c = 0; c < CIN; ++c)
                y += ewd_s[(k * CE + o) * CIN + c] * ez[(k * CIN + c) * Vn + w];
        float val = pc_s[o][0] * y + pc_s[o][1]
                  + pc_s[o][2] * xs[0][w] + pc_s[o][3] * xs[1][w] + pc_s[o][4] * xs[2][w];
        ps[o][w] = fmaxf(val, 0.f);
    }
    __syncthreads();
}

/* DEC ATT */
__global__ __launch_bounds__(512)
void datt_kernel(const float* __restrict__ xb, const float* __restrict__ attE,
                 const float* __restrict__ ewd, const float* __restrict__ pc,
                 const float* __restrict__ dwa, const float* __restrict__ dba,
                 const float* __restrict__ dwb, const float* __restrict__ dbb,
                 float* __restrict__ attp)
{
    __shared__ float attE_s[Kk][Vn][Vn];
    __shared__ float ewd_s[Kk * CE * CIN];
    __shared__ float pc_s[CE][6];
    __shared__ float wa_s[Kk * INTER_ * CE];
    __shared__ float wb_s[Kk * INTER_ * CE];
    __shared__ float ba_s[Kk * INTER_], bb_s[Kk * INTER_];
    __shared__ float xs[CIN][Vn];
    __shared__ float ez[Kk * CIN * Vn];
    __shared__ float ps[CE][Vn];
    __shared__ float fa[Kk][INTER_][Vn], fb[Kk][INTER_][Vn];
    int b = blockIdx.x, s = b % DSEG, n = b / DSEG;
    int tid = threadIdx.x;
    for (int i = tid; i < Kk * VV; i += 512) ((float*)attE_s)[i] = attE[(long)n * Kk * VV + i];
    for (int i = tid; i < Kk * CE * CIN; i += 512) ewd_s[i] = ewd[i];
    for (int i = tid; i < CE * 6; i += 512) ((float*)pc_s)[i] = pc[i];
    for (int i = tid; i < Kk * INTER_ * CE; i += 512) { wa_s[i] = dwa[i]; wb_s[i] = dwb[i]; }
    for (int i = tid; i < Kk * INTER_; i += 512) { ba_s[i] = dba[i]; bb_s[i] = dbb[i]; }
    float acc[4] = {0.f, 0.f, 0.f, 0.f};
    const int TS = Tn / DSEG;
    for (int t = s * TS; t < s * TS + TS; ++t) {
        const float* xp = xb + (long)n * (Mn * CIN * TV) + t * Vn;
        penc_tile(tid, 512, xp, attE_s, ewd_s, pc_s, xs, ez, ps);
        for (int i = tid; i < 2 * Kk * INTER_ * Vn; i += 512) {
            int j = i;
            int sel = j >= Kk * INTER_ * Vn;
            if (sel) j -= Kk * INTER_ * Vn;
            int v = j % Vn, ki = j / Vn;
            const float* W = sel ? wb_s : wa_s;
            float sum = (sel ? bb_s : ba_s)[ki];
            const float* wr = W + ki * CE;
            #pragma unroll
            for (int c = 0; c < CE; ++c) sum += wr[c] * ps[c][v];
            float* dst = sel ? (float*)fb : (float*)fa;
            dst[j] = sum;
        }
        __syncthreads();
        #pragma unroll
        for (int m = 0; m < 4; ++m) {
            int idx = tid + 512 * m;
            if (idx < Kk * VV) {
                int k = idx / VV, r = idx % VV, v = r / Vn, w = r % Vn;
                float a = 0.f;
                #pragma unroll
                for (int i = 0; i < INTER_; ++i) a += fa[k][i][v] * fb[k][i][w];
                acc[m] += a;
            }
        }
    }
    #pragma unroll
    for (int m = 0; m < 4; ++m) {
        int idx = tid + 512 * m;
        if (idx < Kk * VV) {
            int k = idx / VV, r = idx % VV;
            attp[(((long)n * Kk + k) * DSEG + s) * VV + r] = acc[m];
        }
    }
}

/* =================================================================
 * DECY engine: register-tiled dz/dy for BOTH branches.
 * MODE 0: BN stats of raw dec-y -> part[(br*N+n)*TB+tb][128]
 * MODE 1: full dec out (affine+residual+relu) + rr outer product -> out
 * unit u = branch = tid>>7; per-thread 4x4 tile (o-quad x w-quad).
 * ================================================================= */
template<int MODE>
__global__ __launch_bounds__(256)
void decy_kernel(const float* __restrict__ x,
                 const float* __restrict__ attEb,   /* [2][N][K][625] */
                 const float* __restrict__ attDb,   /* [2][N][K][625] */
                 const float* __restrict__ ewd,
                 const float* __restrict__ pcb,     /* [2][64][6] */
                 const float* __restrict__ ycb,     /* [2][64][2] */
                 const float* __restrict__ dwd,     /* [3][64][64] */
                 float* __restrict__ outp)
{
    __shared__ __align__(16) float psT[2][25][64];    /* psT[u][v][c]=p[c][v] */
    __shared__ __align__(16) float dzpd[2][64][36];   /* dz, then pd (MODE1) */
    __shared__ __align__(16) float dwdT[64][68];      /* dwdT[c][o] */
    __shared__ __align__(16) float attD_s[2][25][32]; /* w-padded, zeros */
    __shared__ float ewd_s[576];
    __shared__ float pc_s[2][64][6];
    __shared__ float yc_s[2][64][2];
    __shared__ float xs[2][3][25];
    __shared__ float ez[2][225];

    int b = blockIdx.x, tb = b % TB, n = b / TB;
    int tid = threadIdx.x;
    int u = tid >> 7, tl = tid & 127;
    int to = tl >> 3, tw = tl & 7;
    int o0 = to * 4, w0 = tw * 4;

    for (int i = tid; i < 576; i += 256) ewd_s[i] = ewd[i];
    for (int i = tid; i < 2 * 64 * 6; i += 256) ((float*)pc_s)[i] = pcb[i];
    if (MODE == 1)
        for (int i = tid; i < 2 * 64 * 2; i += 256) ((float*)yc_s)[i] = ycb[i];

    float s1[4] = {0.f, 0.f, 0.f, 0.f}, s2[4] = {0.f, 0.f, 0.f, 0.f};

    for (int tt = 0; tt < TT; ++tt) {
        int t = tb * TT + tt;
        /* ---- penc both branches (each half-block one branch) ---- */
        __syncthreads();
        for (int i = tid; i < 2 * 75; i += 256) {
            int uu = i / 75, r = i % 75, c = r / 25, v = r % 25;
            xs[uu][c][v] = x[(((long)n * 2 + uu) * 3 + c) * TV + t * 25 + v];
        }
        __syncthreads();
        {
            const float* aE = attEb + ((long)(u * N_ + n) * Kk) * VV;
            for (int i = tl; i < 225; i += 128) {
                int w = i % 25, c = (i / 25) % 3, k = i / 75;
                float s = 0.f;
                const float* ar = aE + k * VV + w;
                #pragma unroll
                for (int v = 0; v < 25; ++v) s += xs[u][c][v] * ar[v * 25];
                ez[u][i] = s;
            }
        }
        __syncthreads();
        for (int i = tl; i < 1600; i += 128) {
            int o = i & 63, w = i >> 6;
            float y = 0.f;
            #pragma unroll
            for (int k = 0; k < 3; ++k)
                #pragma unroll
                for (int c = 0; c < 3; ++c)
                    y += ewd_s[(k * 64 + o) * 3 + c] * ez[u][(k * 3 + c) * 25 + w];
            float val = pc_s[u][o][0] * y + pc_s[u][o][1]
                      + pc_s[u][o][2] * xs[u][0][w] + pc_s[u][o][3] * xs[u][1][w]
                      + pc_s[u][o][4] * xs[u][2][w];
            psT[u][w][o] = fmaxf(val, 0.f);
        }
        /* ---- k-loop: dz then dy-accumulate ---- */
        float acc[4][4];
        #pragma unroll
        for (int j = 0; j < 4; ++j)
            #pragma unroll
            for (int m = 0; m < 4; ++m) acc[j][m] = 0.f;
        for (int k = 0; k < 3; ++k) {
            __syncthreads();
            for (int i = tid; i < 1600; i += 256) {
                int w = i & 31, v = (i >> 5) % 25, uu = i / 800;
                attD_s[uu][v][w] = (w < 25)
                    ? attDb[(((long)(uu * N_ + n)) * Kk + k) * VV + v * 25 + w] : 0.f;
            }
            for (int i = tid; i < 4096; i += 256) {
                int o = i >> 6, c = i & 63;
                dwdT[c][o] = dwd[(long)k * 4096 + i];
            }
            __syncthreads();
            /* dz tile (c0..3, w0..3) for unit u */
            {
                float dzt[4][4];
                #pragma unroll
                for (int j = 0; j < 4; ++j)
                    #pragma unroll
                    for (int m = 0; m < 4; ++m) dzt[j][m] = 0.f;
                for (int v = 0; v < 25; ++v) {
                    f4 pa = *(const f4*)&psT[u][v][o0];
                    f4 ad = *(const f4*)&attD_s[u][v][w0];
                    #pragma unroll
                    for (int j = 0; j < 4; ++j)
                        #pragma unroll
                        for (int m = 0; m < 4; ++m) dzt[j][m] += pa[j] * ad[m];
                }
                #pragma unroll
                for (int j = 0; j < 4; ++j) {
                    f4 wv = { dzt[j][0], dzt[j][1], dzt[j][2], dzt[j][3] };
                    *(f4*)&dzpd[u][o0 + j][w0] = wv;
                }
            }
            __syncthreads();
            /* dy accumulate */
            for (int c = 0; c < 64; ++c) {
                f4 wv = *(const f4*)&dwdT[c][o0];
                f4 zv = *(const f4*)&dzpd[u][c][w0];
                #pragma unroll
                for (int j = 0; j < 4; ++j)
                    #pragma unroll
                    for (int m = 0; m < 4; ++m) acc[j][m] += wv[j] * zv[m];
            }
        }
        if (MODE == 0) {
            #pragma unroll
            for (int m = 0; m < 4; ++m) if (w0 + m < 25)
                #pragma unroll
                for (int j = 0; j < 4; ++j) { float a = acc[j][m]; s1[j] += a; s2[j] += a * a; }
        } else {
            __syncthreads();
            #pragma unroll
            for (int j = 0; j < 4; ++j)
                #pragma unroll
                for (int m = 0; m < 4; ++m) {
                    int w = w0 + m;
                    if (w < 25) {
                        float pd = yc_s[u][o0 + j][0] * acc[j][m] + yc_s[u][o0 + j][1]
                                 + psT[u][w][o0 + j];
                        dzpd[u][o0 + j][w] = fmaxf(pd, 0.f);
                    }
                }
            __syncthreads();
            /* rr: 2x2 tiles over (v,w), 169 threads */
            if (tid < 169) {
                int tv = tid / 13, tw2 = tid % 13;
                int v0 = tv * 2, ww0 = tw2 * 2;
                float r00 = 0.f, r01 = 0.f, r10 = 0.f, r11 = 0.f;
                for (int c = 0; c < 64; ++c) {
                    f2 a = *(const f2*)&dzpd[0][c][v0];
                    f2 bb = *(const f2*)&dzpd[1][c][ww0];
                    r00 += a[0] * bb[0]; r01 += a[0] * bb[1];
                    r10 += a[1] * bb[0]; r11 += a[1] * bb[1];
                }
                long ob = ((long)n * Tn + t) * VV;
                if (v0 < 25 && ww0 < 25)         outp[ob + v0 * 25 + ww0] = r00;
                if (v0 < 25 && ww0 + 1 < 25)     outp[ob + v0 * 25 + ww0 + 1] = r01;
                if (v0 + 1 < 25 && ww0 < 25)     outp[ob + (v0 + 1) * 25 + ww0] = r10;
                if (v0 + 1 < 25 && ww0 + 1 < 25) outp[ob + (v0 + 1) * 25 + ww0 + 1] = r11;
            }
        }
    }
    if (MODE == 0) {
        __syncthreads();
        float* red = (float*)dzpd;    /* [2][16][8][8] */
        #pragma unroll
        for (int j = 0; j < 4; ++j) {
            red[(((u * 16 + to) * 8 + tw) * 8) + j * 2 + 0] = s1[j];
            red[(((u * 16 + to) * 8 + tw) * 8) + j * 2 + 1] = s2[j];
        }
        __syncthreads();
        if (tid < 128) {
            int o = tid & 63, u2 = tid >> 6;
            float a1 = 0.f, a2 = 0.f;
            for (int tw3 = 0; tw3 < 8; ++tw3) {
                int base = (((u2 * 16 + (o >> 2)) * 8 + tw3) * 8) + (o & 3) * 2;
                a1 += red[base]; a2 += red[base + 1];
            }
            long pb = (((long)u2 * N_ + n) * TB + tb) * 128;
            outp[pb + o * 2] = a1; outp[pb + o * 2 + 1] = a2;
        }
    }
}

__global__ __launch_bounds__(64)
void dec_fin_kernel(const float* __restrict__ part, int nparts,
                    const float* __restrict__ dg, const float* __restrict__ dbt,
                    float* __restrict__ yc)
{
    int o = threadIdx.x;
    double s1 = 0, s2 = 0;
    for (int b = 0; b < nparts; ++b) { s1 += part[(long)b * 128 + o * 2]; s2 += part[(long)b * 128 + o * 2 + 1]; }
    double cnt = (double)N_ * Tn * Vn;
    double mean = s1 / cnt, var = s2 / cnt - mean * mean;
    double rsig = 1.0 / sqrt(var + 1e-5);
    double a = (double)dg[o] * rsig;
    yc[o * 2 + 0] = (float)a;
    yc[o * 2 + 1] = (float)((double)dbt[o] - a * mean);
}

/* BN stats over (n,v,w) per t */
__global__ __launch_bounds__(256)
void rrbn_kernel(const float* __restrict__ rr, float* __restrict__ tstats)
{
    int t = blockIdx.x;
    double s = 0.0, s2 = 0.0;
    for (int idx = threadIdx.x; idx < N_ * VV; idx += 256) {
        int n = idx / VV, j = idx % VV;
        float v = rr[((long)n * Tn + t) * VV + j];
        s += v; s2 += (double)v * v;
    }
    __shared__ double rs[256], rs2[256];
    int tid = threadIdx.x;
    rs[tid] = s; rs2[tid] = s2;
    __syncthreads();
    for (int off = 128; off > 0; off >>= 1) {
        if (tid < off) { rs[tid] += rs[tid + off]; rs2[tid] += rs2[tid + off]; }
        __syncthreads();
    }
    if (tid == 0) {
        double cnt = (double)N_ * VV;
        double mean = rs[0] / cnt;
        double var = rs2[0] / cnt - mean * mean;
        tstats[t * 2 + 0] = (float)mean;
        tstats[t * 2 + 1] = (float)(1.0 / sqrt(var + 1e-5));
    }
}

/* FINAL */
__global__ __launch_bounds__(128)
void final_kernel(const float* __restrict__ tstats,
                  const float* __restrict__ x, const float* __restrict__ iparam,
                  const float* __restrict__ tgamma, const float* __restrict__ tbeta,
                  float* out)
{
    int b = blockIdx.x;
    int t = b % Tn, n = b / Tn;
    __shared__ float xa_s[CIN][Vn], xb_s[CIN][Vn];
    __shared__ float ram_s[VV];
    __shared__ float da_s[Vn], db_s[Vn];
    __shared__ float varc[CIN];
    __shared__ float abf;
    int tid = threadIdx.x;

    for (int idx = tid; idx < 2 * CIN * Vn; idx += 128) {
        int half = idx / (CIN * Vn);
        int r = idx % (CIN * Vn);
        int c = r / Vn, v = r % Vn;
        float val = x[(((long)n * Mn + half) * CIN + c) * TV + t * Vn + v];
        if (half == 0) xa_s[c][v] = val; else xb_s[c][v] = val;
    }
    __syncthreads();
    if (tid < CIN) {
        float s = 0.f, s2 = 0.f;
        #pragma unroll
        for (int v = 0; v < Vn; ++v) { float q = xb_s[tid][v]; s += q; s2 += q * q; }
        float mean = s / Vn;
        varc[tid] = (s2 - Vn * mean * mean) / (Vn - 1);
    }
    __syncthreads();
    if (tid == 0) {
        float absum = varc[0] + varc[1] + varc[2];
        abf = (absum < 1e-4f) ? 0.f : 1.f;
    }
    float pct = 0.5f * (tanhf(iparam[0]) + 1.f);
    float mt = tstats[t * 2], rt = tstats[t * 2 + 1];
    float gt = tgamma[t], bt = tbeta[t];
    __syncthreads();

    for (int idx = tid; idx < VV; idx += 128) {
        int v = idx / Vn, w = idx % Vn;
        float rrv = out[(long)b * VV + idx];
        float rbn = gt * (rrv - mt) * rt + bt;
        float ramr = 0.5f * (tanhf(rbn) + 1.f);
        float gsum = 0.f;
        #pragma unroll
        for (int c = 0; c < CIN; ++c) {
            float d = expf(xa_s[c][v]) * expf(-xb_s[c][w]);
            float l = logf(d + 1e-5f);
            gsum += l * l;
        }
        float ramg = expf(-(1.f / 3.f) * gsum);
        float ram = pct * ramr + (1.f - pct) * ramg;
        ram *= abf;
        if (ram < 0.5f) ram = 0.f;
        ram_s[idx] = ram;
    }
    __syncthreads();
    if (tid < Vn) {
        float s = 0.f;
        #pragma unroll
        for (int v = 0; v < Vn; ++v) s += ram_s[v * Vn + tid];
        da_s[tid] = s;
    } else if (tid >= 64 && tid < 64 + Vn) {
        int v = tid - 64;
        float s = 0.f;
        #pragma unroll
        for (int w = 0; w < Vn; ++w) s += ram_s[v * Vn + w];
        db_s[v] = s;
    }
    __syncthreads();
    for (int idx = tid; idx < VV; idx += 128) {
        int v = idx / Vn, w = idx % Vn;
        float ram = ram_s[idx];
        out[(long)b * VV + idx] = ram * rsqrtf(db_s[v] * da_s[w] + 1e-5f);
    }
}

/* ================================================================= */
extern "C" void kernel_launch(void* const* d_in, const int* in_sizes, int n_in,
                              void* d_out, int out_size, void* d_ws, size_t ws_size,
                              hipStream_t stream)
{
    const float* x    = (const float*)d_in[0];
    const float* A    = (const float*)d_in[1];
    const float* ip   = (const float*)d_in[2];
    const float* rg   = (const float*)d_in[3];
    const float* rbta = (const float*)d_in[4];
    const float* ePA  = (const float*)d_in[5];
    const float* ewa  = (const float*)d_in[6];
    const float* eba  = (const float*)d_in[7];
    const float* ewb  = (const float*)d_in[8];
    const float* ebb  = (const float*)d_in[9];
    const float* ewd  = (const float*)d_in[10];
    const float* ebd  = (const float*)d_in[11];  (void)ebd;
    const float* eg   = (const float*)d_in[12];
    const float* ebt  = (const float*)d_in[13];
    const float* edw  = (const float*)d_in[14];
    const float* edb  = (const float*)d_in[15];
    const float* edg  = (const float*)d_in[16];
    const float* edbt = (const float*)d_in[17];
    const float* dPA  = (const float*)d_in[18];
    const float* dwa  = (const float*)d_in[19];
    const float* dba  = (const float*)d_in[20];
    const float* dwb  = (const float*)d_in[21];
    const float* dbb  = (const float*)d_in[22];
    const float* dwd  = (const float*)d_in[23];
    const float* dbd  = (const float*)d_in[24];  (void)dbd;
    const float* dg   = (const float*)d_in[25];
    const float* dbt  = (const float*)d_in[26];

    if (ws_size < (size_t)WS_REQ * sizeof(float)) return;

    float* ws   = (float*)d_ws;
    float* attp = ws + OFF_ATTP;
    float* part = ws + OFF_PART;
    float* attE = ws + OFF_ATTE;
    float* attD = ws + OFF_ATTD;
    double* covp = (double*)(ws + OFF_COV);
    float* pc   = ws + OFF_PC;
    float* yc   = ws + OFF_YC;
    float* tst  = ws + OFF_TST;
    float* outf = (float*)d_out;

    const long XN = (long)Mn * CIN * TV;

    for (int br = 0; br < 2; ++br) {
        const float* xbr = x + (long)br * CIN * TV;
        float* attE_br = attE + (long)br * (N_ * Kk * VV);
        float* attD_br = attD + (long)br * (N_ * Kk * VV);
        float* pc_br = pc + br * (CE * 6);

        att_kernel<<<N_ * Kk * ESEG, 640, 0, stream>>>(
            xbr, XN, TV, ewa, eba, ewb, ebb, attp);
        softmax_kernel<ESEG><<<N_ * Kk, 256, 0, stream>>>(attp, A, ePA, attE_br);
        xcov_kernel<<<120, 256, 0, stream>>>(xbr, XN, TV, covp);
        ey_stat_kernel<<<N_ * EYB, 256, 0, stream>>>(xbr, attE_br, ewd, part);
        enc_fin_kernel<<<1, 64, 0, stream>>>(part, N_ * EYB, covp, 120,
                                             eg, ebt, edw, edb, edg, edbt, pc_br);
        datt_kernel<<<N_ * DSEG, 512, 0, stream>>>(
            xbr, attE_br, ewd, pc_br, dwa, dba, dwb, dbb, attp);
        softmax_kernel<DSEG><<<N_ * Kk, 256, 0, stream>>>(attp, A, dPA, attD_br);
    }

    /* merged dec-y stats for both branches */
    decy_kernel<0><<<N_ * TB, 256, 0, stream>>>(x, attE, attD, ewd, pc, pc, dwd, part);
    dec_fin_kernel<<<1, 64, 0, stream>>>(part, N_ * TB, dg, dbt, yc);
    dec_fin_kernel<<<1, 64, 0, stream>>>(part + (long)N_ * TB * 128, N_ * TB,
                                         dg, dbt, yc + CE * 2);
    /* full dec out + rr */
    decy_kernel<1><<<N_ * TB, 256, 0, stream>>>(x, attE, attD, ewd, pc, yc, dwd, outf);

    rrbn_kernel<<<Tn, 256, 0, stream>>>(outf, tst);
    final_kernel<<<N_ * Tn, 128, 0, stream>>>(tst, x, ip, rg, rbta, outf);
}